// Round 2
// baseline (6133.369 us; speedup 1.0000x reference)
//
#include <hip/hip_runtime.h>
#include <hip/hip_bf16.h>
#include <math.h>

typedef __hip_bfloat16 bf16;

__device__ __forceinline__ float b2f(bf16 v) { return __bfloat162float(v); }
__device__ __forceinline__ bf16  f2b(float v) { return __float2bfloat16(v); }

constexpr int Bc = 2, Tc = 1024, Dc = 2048, Hc = 16, HKVc = 4, DHc = 128, Fc = 5632;
constexpr int Mrows = Bc * Tc;  // 2048

union U8 { uint4 v; bf16 h[8]; };

// Load 8 contiguous elements at element offset `off` from `base`, whose true
// dtype is fp32 if isf32 else bf16; return packed bf16x8. Offset must be 8-elem
// aligned. Branch is wave-uniform.
__device__ __forceinline__ uint4 ld8(const void* base, size_t off, int isf32) {
  U8 u;
  if (isf32) {
    const float* p = (const float*)base + off;
    float4 a = *reinterpret_cast<const float4*>(p);
    float4 b = *reinterpret_cast<const float4*>(p + 4);
    u.h[0] = f2b(a.x); u.h[1] = f2b(a.y); u.h[2] = f2b(a.z); u.h[3] = f2b(a.w);
    u.h[4] = f2b(b.x); u.h[5] = f2b(b.y); u.h[6] = f2b(b.z); u.h[7] = f2b(b.w);
  } else {
    u.v = *reinterpret_cast<const uint4*>((const bf16*)base + off);
  }
  return u.v;
}

__device__ __forceinline__ float ld1(const void* base, size_t off, int isf32) {
  return isf32 ? ((const float*)base)[off] : b2f(((const bf16*)base)[off]);
}

// ------------------------------------------------------------- dtype probe ---
// If storage is fp32, bf16-interpreting element pairs makes the EVEN halves the
// low mantissa bits -> uniformly random exponent fields. Vote over 64 samples.
__global__ void detect_k(const void* __restrict__ x, int* __restrict__ flag) {
  if (threadIdx.x == 0 && blockIdx.x == 0) {
    const unsigned short* u = (const unsigned short*)x;
    int cnt = 0;
    for (int i = 0; i < 128; i += 2) {
      int e = (u[i] >> 7) & 0xFF;
      if (e > 134 || (e != 0 && e < 100)) ++cnt;  // |v|>~128 or |v|<2^-27: garbage
    }
    *flag = (cnt >= 8) ? 1 : 0;
  }
}

// ---------------------------------------------------------------- RMSNorm ---
// XMODE 0: x dtype per flag (bf16/f32). XMODE 1: x is fp32 (internal residual).
template <int XMODE>
__global__ __launch_bounds__(256) void rmsnorm_k(const void* __restrict__ x,
                                                 const void* __restrict__ w,
                                                 bf16* __restrict__ out,
                                                 const int* __restrict__ flagp) {
  const int isf32 = *flagp;
  const int xf = (XMODE == 1) ? 1 : isf32;
  const size_t rbase = (size_t)blockIdx.x * Dc;
  float ss = 0.f;
  for (int i = threadIdx.x; i < Dc; i += 256) {
    float v = ld1(x, rbase + i, xf);
    ss += v * v;
  }
#pragma unroll
  for (int off = 32; off > 0; off >>= 1) ss += __shfl_down(ss, off, 64);
  __shared__ float red[4];
  const int lane = threadIdx.x & 63, wid = threadIdx.x >> 6;
  if (lane == 0) red[wid] = ss;
  __syncthreads();
  const float total = red[0] + red[1] + red[2] + red[3];
  const float scale = rsqrtf(total / (float)Dc + 1e-6f);
  bf16* orow = out + rbase;
  for (int i = threadIdx.x; i < Dc; i += 256)
    orow[i] = f2b(ld1(x, rbase + i, xf) * scale * ld1(w, i, isf32));
}

// ------------------------------------------------------------- tiled GEMM ---
// C[M,N] = A[M,K] @ B[K,N]; A is always internal bf16. B is an input (dual).
// MODE 0: out bf16 (ws).
// MODE 1: out f32 (ws) = input residual (dual dtype) + acc.   (wo proj)
// MODE 2: out d_out (dual dtype) = f32 ws residual + acc.     (w2 proj)
template <int MODE>
__global__ __launch_bounds__(256) void gemm_tiled(const bf16* __restrict__ A,
                                                  const void* __restrict__ Bw,
                                                  const void* __restrict__ Res,
                                                  void* __restrict__ Out,
                                                  int M, int N, int K,
                                                  const int* __restrict__ flagp) {
  const int isf32 = *flagp;
  __shared__ bf16 As[64][33];
  __shared__ bf16 Bs[32][72];
  const int tid = threadIdx.x;
  const int tx = tid & 15, ty = tid >> 4;
  const int bn = blockIdx.x * 64, bm = blockIdx.y * 64;
  const int a_row = tid >> 2, a_col = (tid & 3) * 8;
  const int b_row = tid >> 3, b_col = (tid & 7) * 8;
  float acc[4][4] = {{0.f}};
  for (int k0 = 0; k0 < K; k0 += 32) {
    uint4 av = *reinterpret_cast<const uint4*>(A + (size_t)(bm + a_row) * K + k0 + a_col);
    uint4 bv = ld8(Bw, (size_t)(k0 + b_row) * N + bn + b_col, isf32);
    __syncthreads();
    *reinterpret_cast<uint4*>(&Bs[b_row][b_col]) = bv;
    const bf16* ah = reinterpret_cast<const bf16*>(&av);
#pragma unroll
    for (int j = 0; j < 8; ++j) As[a_row][a_col + j] = ah[j];
    __syncthreads();
#pragma unroll
    for (int kk = 0; kk < 32; ++kk) {
      float a[4], b[4];
#pragma unroll
      for (int i = 0; i < 4; ++i) a[i] = b2f(As[ty * 4 + i][kk]);
#pragma unroll
      for (int j = 0; j < 4; ++j) b[j] = b2f(Bs[kk][tx * 4 + j]);
#pragma unroll
      for (int i = 0; i < 4; ++i)
#pragma unroll
        for (int j = 0; j < 4; ++j) acc[i][j] = fmaf(a[i], b[j], acc[i][j]);
    }
  }
#pragma unroll
  for (int i = 0; i < 4; ++i) {
    const int row = bm + ty * 4 + i;
#pragma unroll
    for (int j = 0; j < 4; ++j) {
      const int col = bn + tx * 4 + j;
      const size_t idx = (size_t)row * N + col;
      if (MODE == 0) {
        ((bf16*)Out)[idx] = f2b(acc[i][j]);
      } else if (MODE == 1) {
        float r = ld1(Res, idx, isf32);
        ((float*)Out)[idx] = r + acc[i][j];
      } else {
        float v = ((const float*)Res)[idx] + acc[i][j];
        if (isf32) ((float*)Out)[idx] = v;
        else       ((bf16*)Out)[idx]  = f2b(v);
      }
    }
  }
}

// ------------------------------------------------- fused FFN gate GEMM ------
// Act = silu(A@W1) * (A@W3); A internal bf16, W1/W3 inputs (dual), out bf16 ws.
__global__ __launch_bounds__(256) void gemm_ffn(const bf16* __restrict__ A,
                                                const void* __restrict__ W1,
                                                const void* __restrict__ W3,
                                                bf16* __restrict__ Act,
                                                int M, int N, int K,
                                                const int* __restrict__ flagp) {
  const int isf32 = *flagp;
  __shared__ bf16 As[64][33];
  __shared__ bf16 B1s[32][72];
  __shared__ bf16 B3s[32][72];
  const int tid = threadIdx.x;
  const int tx = tid & 15, ty = tid >> 4;
  const int bn = blockIdx.x * 64, bm = blockIdx.y * 64;
  const int a_row = tid >> 2, a_col = (tid & 3) * 8;
  const int b_row = tid >> 3, b_col = (tid & 7) * 8;
  float acc1[4][4] = {{0.f}}, acc3[4][4] = {{0.f}};
  for (int k0 = 0; k0 < K; k0 += 32) {
    uint4 av = *reinterpret_cast<const uint4*>(A + (size_t)(bm + a_row) * K + k0 + a_col);
    uint4 b1v = ld8(W1, (size_t)(k0 + b_row) * N + bn + b_col, isf32);
    uint4 b3v = ld8(W3, (size_t)(k0 + b_row) * N + bn + b_col, isf32);
    __syncthreads();
    *reinterpret_cast<uint4*>(&B1s[b_row][b_col]) = b1v;
    *reinterpret_cast<uint4*>(&B3s[b_row][b_col]) = b3v;
    const bf16* ah = reinterpret_cast<const bf16*>(&av);
#pragma unroll
    for (int j = 0; j < 8; ++j) As[a_row][a_col + j] = ah[j];
    __syncthreads();
#pragma unroll
    for (int kk = 0; kk < 32; ++kk) {
      float a[4], b1[4], b3[4];
#pragma unroll
      for (int i = 0; i < 4; ++i) a[i] = b2f(As[ty * 4 + i][kk]);
#pragma unroll
      for (int j = 0; j < 4; ++j) b1[j] = b2f(B1s[kk][tx * 4 + j]);
#pragma unroll
      for (int j = 0; j < 4; ++j) b3[j] = b2f(B3s[kk][tx * 4 + j]);
#pragma unroll
      for (int i = 0; i < 4; ++i)
#pragma unroll
        for (int j = 0; j < 4; ++j) {
          acc1[i][j] = fmaf(a[i], b1[j], acc1[i][j]);
          acc3[i][j] = fmaf(a[i], b3[j], acc3[i][j]);
        }
    }
  }
#pragma unroll
  for (int i = 0; i < 4; ++i) {
    const int row = bm + ty * 4 + i;
#pragma unroll
    for (int j = 0; j < 4; ++j) {
      const int col = bn + tx * 4 + j;
      float g = acc1[i][j], u = acc3[i][j];
      float sg = g / (1.f + __expf(-g));
      Act[(size_t)row * N + col] = f2b(sg * u);
    }
  }
}

// -------------------------------------------------------------------- RoPE --
// qk: (B,T,NH,DH) internal bf16, in-place; cos/sin are inputs (dual dtype).
__global__ void rope_k(bf16* __restrict__ qk, const void* __restrict__ cosb,
                       const void* __restrict__ sinb, int NH, int total,
                       const int* __restrict__ flagp) {
  const int isf32 = *flagp;
  int idx = blockIdx.x * 256 + threadIdx.x;
  if (idx >= total) return;
  const int i = idx & 63;
  const int h = (idx >> 6) % NH;
  const int bt = idx / (64 * NH);
  const int t = bt & (Tc - 1);
  const size_t base = ((size_t)bt * NH + h) * DHc + i * 2;
  float x0 = b2f(qk[base]), x1 = b2f(qk[base + 1]);
  float c = ld1(cosb, t * 64 + i, isf32);
  float s = ld1(sinb, t * 64 + i, isf32);
  qk[base] = f2b(x0 * c - x1 * s);
  qk[base + 1] = f2b(x0 * s + x1 * c);
}

// --------------------------------------------------------------- attention --
// one block (128 threads) per (b,h,t) query row; causal softmax over s<=t.
// q/k/v/out are all internal bf16 workspace buffers.
__global__ __launch_bounds__(128) void attn_k(const bf16* __restrict__ q,
                                              const bf16* __restrict__ k,
                                              const bf16* __restrict__ v,
                                              bf16* __restrict__ out) {
  const int bid = blockIdx.x;
  const int t = bid & (Tc - 1);
  const int h = (bid >> 10) & (Hc - 1);
  const int b = bid >> 14;
  const int kv = h >> 2;  // h / G, G = 4
  const int tid = threadIdx.x;
  __shared__ float qs[DHc];
  __shared__ float sc[Tc];
  __shared__ float wmax[2], wsum[2];
  const float scale = 0.08838834764831845f;  // 1/sqrt(128)
  qs[tid] = b2f(q[((size_t)(b * Tc + t) * Hc + h) * DHc + tid]) * scale;
  __syncthreads();
  const int len = t + 1;
  float lmax = -1e30f;
  const bf16* kbase = k + ((size_t)b * Tc * HKVc + kv) * DHc;
  for (int s = tid; s < len; s += 128) {
    const uint4* kp = reinterpret_cast<const uint4*>(kbase + (size_t)s * HKVc * DHc);
    float dot = 0.f;
#pragma unroll
    for (int c = 0; c < DHc / 8; ++c) {
      U8 uv; uv.v = kp[c];
#pragma unroll
      for (int j = 0; j < 8; ++j) dot += qs[c * 8 + j] * b2f(uv.h[j]);
    }
    sc[s] = dot;
    lmax = fmaxf(lmax, dot);
  }
#pragma unroll
  for (int off = 32; off > 0; off >>= 1) lmax = fmaxf(lmax, __shfl_down(lmax, off, 64));
  const int lane = tid & 63, wid = tid >> 6;
  if (lane == 0) wmax[wid] = lmax;
  __syncthreads();
  const float m = fmaxf(wmax[0], wmax[1]);
  float lsum = 0.f;
  for (int s = tid; s < len; s += 128) {
    float e = __expf(sc[s] - m);
    sc[s] = e;
    lsum += e;
  }
#pragma unroll
  for (int off = 32; off > 0; off >>= 1) lsum += __shfl_down(lsum, off, 64);
  if (lane == 0) wsum[wid] = lsum;
  __syncthreads();
  const float inv_denom = 1.f / (wsum[0] + wsum[1]);
  const bf16* vbase = v + ((size_t)b * Tc * HKVc + kv) * DHc + tid;
  float accd = 0.f;
  for (int s = 0; s < len; ++s) accd += sc[s] * b2f(vbase[(size_t)s * HKVc * DHc]);
  out[((size_t)(b * Tc + t) * Hc + h) * DHc + tid] = f2b(accd * inv_denom);
}

// ------------------------------------------------------------------ launch --
extern "C" void kernel_launch(void* const* d_in, const int* in_sizes, int n_in,
                              void* d_out, int out_size, void* d_ws, size_t ws_size,
                              hipStream_t stream) {
  const void* x    = d_in[0];
  const void* fcos = d_in[1];
  const void* fsin = d_in[2];
  const void* wn1  = d_in[3];
  const void* wn2  = d_in[4];
  const void* wq   = d_in[5];
  const void* wk   = d_in[6];
  const void* wv   = d_in[7];
  const void* wo   = d_in[8];
  const void* w1   = d_in[9];
  const void* w2   = d_in[10];
  const void* w3   = d_in[11];

  char* p = (char*)d_ws;
  int* flag = (int*)p;  p += 256;
  bf16* xn = (bf16*)p;  p += (size_t)Mrows * Dc * 2;          // 8 MB (reused as h)
  bf16* qb = (bf16*)p;  p += (size_t)Mrows * Hc * DHc * 2;    // 8 MB
  bf16* kb = (bf16*)p;  p += (size_t)Mrows * HKVc * DHc * 2;  // 2 MB
  bf16* vb = (bf16*)p;  p += (size_t)Mrows * HKVc * DHc * 2;  // 2 MB
  bf16* ao = (bf16*)p;  p += (size_t)Mrows * Dc * 2;          // 8 MB
  float* xat = (float*)p; p += (size_t)Mrows * Dc * 4;        // 16 MB fp32 attn residual
  bf16* act = (bf16*)p; p += (size_t)Mrows * Fc * 2;          // 23 MB
  bf16* hb = xn;  // xn dead after QKV projections

  const dim3 blk(256);
  detect_k<<<1, 64, 0, stream>>>(x, flag);
  rmsnorm_k<0><<<Mrows, blk, 0, stream>>>(x, wn1, xn, flag);
  gemm_tiled<0><<<dim3(Dc / 64, Mrows / 64), blk, 0, stream>>>(xn, wq, nullptr, qb, Mrows, Hc * DHc, Dc, flag);
  gemm_tiled<0><<<dim3((HKVc * DHc) / 64, Mrows / 64), blk, 0, stream>>>(xn, wk, nullptr, kb, Mrows, HKVc * DHc, Dc, flag);
  gemm_tiled<0><<<dim3((HKVc * DHc) / 64, Mrows / 64), blk, 0, stream>>>(xn, wv, nullptr, vb, Mrows, HKVc * DHc, Dc, flag);
  {
    int total = Mrows * Hc * 64;
    rope_k<<<(total + 255) / 256, blk, 0, stream>>>(qb, fcos, fsin, Hc, total, flag);
  }
  {
    int total = Mrows * HKVc * 64;
    rope_k<<<(total + 255) / 256, blk, 0, stream>>>(kb, fcos, fsin, HKVc, total, flag);
  }
  attn_k<<<Bc * Hc * Tc, dim3(128), 0, stream>>>(qb, kb, vb, ao);
  gemm_tiled<1><<<dim3(Dc / 64, Mrows / 64), blk, 0, stream>>>(ao, wo, x, xat, Mrows, Dc, Dc, flag);
  rmsnorm_k<1><<<Mrows, blk, 0, stream>>>(xat, wn2, hb, flag);
  gemm_ffn<<<dim3(Fc / 64, Mrows / 64), blk, 0, stream>>>(hb, w1, w3, act, Mrows, Fc, Dc, flag);
  gemm_tiled<2><<<dim3(Dc / 64, Mrows / 64), blk, 0, stream>>>(act, w2, xat, d_out, Mrows, Dc, Fc, flag);
}

// Round 4
// 1678.860 us; speedup vs baseline: 3.6533x; 3.6533x over previous
//
#include <hip/hip_runtime.h>
#include <hip/hip_bf16.h>
#include <math.h>

typedef __hip_bfloat16 bf16;
typedef __attribute__((ext_vector_type(8))) short bf16x8;   // 8 bf16 = 4 VGPR
typedef __attribute__((ext_vector_type(4))) float f32x4;

__device__ __forceinline__ float b2f(bf16 v) { return __bfloat162float(v); }
__device__ __forceinline__ bf16  f2b(float v) { return __float2bfloat16(v); }

constexpr int Bc = 2, Tc = 1024, Dc = 2048, Hc = 16, HKVc = 4, DHc = 128, Fc = 5632;
constexpr int Mr = Bc * Tc;                      // 2048 rows
constexpr int Nqkv = Hc * DHc + 2 * HKVc * DHc;  // 3072

// async 16B global->LDS (lands at wave-uniform base + lane*16)
__device__ __forceinline__ void g2l16(void* lds, const void* g) {
  __builtin_amdgcn_global_load_lds(
      (const __attribute__((address_space(1))) unsigned int*)g,
      (__attribute__((address_space(3))) unsigned int*)lds, 16, 0, 0);
}

// ------------------------------------------------------- transpose + cast ---
// src fp32 [K][N] row-major  ->  dst bf16 [N][K] row-major (B^T for MFMA GEMM)
__global__ __launch_bounds__(256) void tcast_k(const float* __restrict__ src,
                                               bf16* __restrict__ dst,
                                               int N, int K) {
  __shared__ bf16 tile[64][68];
  const int t = threadIdx.x;
  const int n0 = blockIdx.x * 64, k0 = blockIdx.y * 64;
#pragma unroll
  for (int it = 0; it < 4; ++it) {
    const int kl = it * 16 + (t >> 4);
    const int nl = (t & 15) * 4;
    float4 v = *reinterpret_cast<const float4*>(src + (size_t)(k0 + kl) * N + n0 + nl);
    tile[kl][nl]     = f2b(v.x);
    tile[kl][nl + 1] = f2b(v.y);
    tile[kl][nl + 2] = f2b(v.z);
    tile[kl][nl + 3] = f2b(v.w);
  }
  __syncthreads();
  union { uint4 u; bf16 h[8]; } o;   // 16 B (was ushort4=8B: half-stored weights!)
#pragma unroll
  for (int it = 0; it < 2; ++it) {
    const int nl = it * 32 + (t >> 3);
    const int kl = (t & 7) * 8;
#pragma unroll
    for (int j = 0; j < 8; ++j) o.h[j] = tile[kl + j][nl];
    *reinterpret_cast<uint4*>(dst + (size_t)(n0 + nl) * K + k0 + kl) = o.u;
  }
}

// ---------------------------------------------------------------- RMSNorm ---
__global__ __launch_bounds__(256) void rmsnorm_k(const float* __restrict__ x,
                                                 const float* __restrict__ w,
                                                 bf16* __restrict__ out) {
  const size_t rbase = (size_t)blockIdx.x * Dc;
  float ss = 0.f;
  for (int i = threadIdx.x; i < Dc; i += 256) {
    float v = x[rbase + i];
    ss += v * v;
  }
#pragma unroll
  for (int off = 32; off > 0; off >>= 1) ss += __shfl_down(ss, off, 64);
  __shared__ float red[4];
  const int lane = threadIdx.x & 63, wid = threadIdx.x >> 6;
  if (lane == 0) red[wid] = ss;
  __syncthreads();
  const float scale = rsqrtf((red[0] + red[1] + red[2] + red[3]) / (float)Dc + 1e-6f);
  for (int i = threadIdx.x; i < Dc; i += 256)
    out[rbase + i] = f2b(x[rbase + i] * scale * w[i]);
}

// ----------------------------------------------------- MFMA GEMM (m97-ish) --
// C[M][N] = A[M][K] (bf16 row-major) x Bt[N][K]^T (bf16 row-major).
// 128x128 tile, BK=32, 4 waves in 2x2, 16 MFMA(16x16x32)/wave/K-iter.
// ADDRES: out fp32 = Res fp32 + acc, else out bf16 = acc.
template <bool ADDRES>
__global__ __launch_bounds__(256) void gemm128(const bf16* __restrict__ A,
                                               const bf16* __restrict__ Bt,
                                               const float* __restrict__ Res,
                                               void* __restrict__ Out,
                                               int N, int K) {
  __shared__ __align__(16) bf16 As[128 * 32];
  __shared__ __align__(16) bf16 Bs[128 * 32];
  const int t = threadIdx.x;
  const int bm = blockIdx.y * 128, bn = blockIdx.x * 128;
  const int lane = t & 63, wv = t >> 6;
  const int wm = (wv & 1) * 64, wn = (wv >> 1) * 64;
  // staging: thread covers 16B; rows sr and sr+64
  const int sr = t >> 2, sc = (t & 3) * 8;
  const bf16* ga = A + (size_t)(bm + sr) * K + sc;
  const bf16* gb = Bt + (size_t)(bn + sr) * K + sc;
  bf16* lA0 = As + sr * 32 + sc;
  bf16* lA1 = As + (64 + sr) * 32 + sc;
  bf16* lB0 = Bs + sr * 32 + sc;
  bf16* lB1 = Bs + (64 + sr) * 32 + sc;
  const size_t rstep = (size_t)64 * K;
  f32x4 acc[4][4] = {};
  const int fr = lane & 15, fko = (lane >> 4) * 8;
  for (int k0 = 0; k0 < K; k0 += 32) {
    __syncthreads();
    g2l16(lA0, ga + k0);
    g2l16(lA1, ga + rstep + k0);
    g2l16(lB0, gb + k0);
    g2l16(lB1, gb + rstep + k0);
    __syncthreads();
    bf16x8 af[4], bff[4];
#pragma unroll
    for (int i = 0; i < 4; ++i)
      af[i] = *reinterpret_cast<const bf16x8*>(As + (wm + i * 16 + fr) * 32 + fko);
#pragma unroll
    for (int j = 0; j < 4; ++j)
      bff[j] = *reinterpret_cast<const bf16x8*>(Bs + (wn + j * 16 + fr) * 32 + fko);
#pragma unroll
    for (int i = 0; i < 4; ++i)
#pragma unroll
      for (int j = 0; j < 4; ++j)
        acc[i][j] = __builtin_amdgcn_mfma_f32_16x16x32_bf16(af[i], bff[j], acc[i][j], 0, 0, 0);
  }
  const int er = (lane >> 4) * 4, ec = lane & 15;
#pragma unroll
  for (int i = 0; i < 4; ++i)
#pragma unroll
    for (int j = 0; j < 4; ++j) {
      const int row = bm + wm + i * 16 + er;
      const int col = bn + wn + j * 16 + ec;
#pragma unroll
      for (int r = 0; r < 4; ++r) {
        const size_t idx = (size_t)(row + r) * N + col;
        if (ADDRES) ((float*)Out)[idx] = Res[idx] + acc[i][j][r];
        else        ((bf16*)Out)[idx] = f2b(acc[i][j][r]);
      }
    }
}

// --------------------------------------------- fused FFN dual-B MFMA GEMM ---
// act[M][F] = silu(A@W1) * (A@W3); W1t/W3t are [F][K] bf16. Tile 64(M)x128(F),
// BK=32; 4 waves each 64x32 per B; dual accumulators.
__global__ __launch_bounds__(256) void ffn_dual(const bf16* __restrict__ A,
                                                const bf16* __restrict__ W1t,
                                                const bf16* __restrict__ W3t,
                                                bf16* __restrict__ act,
                                                int K) {
  __shared__ __align__(16) bf16 As[64 * 32];
  __shared__ __align__(16) bf16 B1s[128 * 32];
  __shared__ __align__(16) bf16 B3s[128 * 32];
  const int t = threadIdx.x;
  const int bm = blockIdx.y * 64, bn = blockIdx.x * 128;
  const int lane = t & 63, wv = t >> 6;
  const int wn = wv * 32;
  const int sr = t >> 2, sc = (t & 3) * 8;
  const bf16* ga = A + (size_t)(bm + sr) * K + sc;
  const bf16* g1 = W1t + (size_t)(bn + sr) * K + sc;
  const bf16* g3 = W3t + (size_t)(bn + sr) * K + sc;
  bf16* lA = As + sr * 32 + sc;
  bf16* l10 = B1s + sr * 32 + sc;
  bf16* l11 = B1s + (64 + sr) * 32 + sc;
  bf16* l30 = B3s + sr * 32 + sc;
  bf16* l31 = B3s + (64 + sr) * 32 + sc;
  const size_t rstep = (size_t)64 * K;
  f32x4 acc1[4][2] = {}, acc3[4][2] = {};
  const int fr = lane & 15, fko = (lane >> 4) * 8;
  for (int k0 = 0; k0 < K; k0 += 32) {
    __syncthreads();
    g2l16(lA, ga + k0);
    g2l16(l10, g1 + k0);
    g2l16(l11, g1 + rstep + k0);
    g2l16(l30, g3 + k0);
    g2l16(l31, g3 + rstep + k0);
    __syncthreads();
    bf16x8 af[4], b1[2], b3[2];
#pragma unroll
    for (int i = 0; i < 4; ++i)
      af[i] = *reinterpret_cast<const bf16x8*>(As + (i * 16 + fr) * 32 + fko);
#pragma unroll
    for (int j = 0; j < 2; ++j) {
      b1[j] = *reinterpret_cast<const bf16x8*>(B1s + (wn + j * 16 + fr) * 32 + fko);
      b3[j] = *reinterpret_cast<const bf16x8*>(B3s + (wn + j * 16 + fr) * 32 + fko);
    }
#pragma unroll
    for (int i = 0; i < 4; ++i)
#pragma unroll
      for (int j = 0; j < 2; ++j) {
        acc1[i][j] = __builtin_amdgcn_mfma_f32_16x16x32_bf16(af[i], b1[j], acc1[i][j], 0, 0, 0);
        acc3[i][j] = __builtin_amdgcn_mfma_f32_16x16x32_bf16(af[i], b3[j], acc3[i][j], 0, 0, 0);
      }
  }
  const int er = (lane >> 4) * 4, ec = lane & 15;
#pragma unroll
  for (int i = 0; i < 4; ++i)
#pragma unroll
    for (int j = 0; j < 2; ++j) {
      const int row = bm + i * 16 + er;
      const int col = bn + wn + j * 16 + ec;
#pragma unroll
      for (int r = 0; r < 4; ++r) {
        const float g = acc1[i][j][r], u = acc3[i][j][r];
        const float sg = g / (1.f + __expf(-g));
        act[(size_t)(row + r) * Fc + col] = f2b(sg * u);
      }
    }
}

// -------------------------------------------------------------------- RoPE --
// in-place on qkv rows (stride Nqkv); head block at colOff + h*DH.
__global__ void rope_k(bf16* __restrict__ base, const float* __restrict__ cosb,
                       const float* __restrict__ sinb, int NH, int colOff, int total) {
  const int idx = blockIdx.x * 256 + threadIdx.x;
  if (idx >= total) return;
  const int i = idx & 63;
  const int h = (idx >> 6) % NH;
  const int bt = idx / (64 * NH);
  const int tpos = bt & (Tc - 1);
  bf16* p = base + (size_t)bt * Nqkv + colOff + h * DHc + i * 2;
  const float x0 = b2f(p[0]), x1 = b2f(p[1]);
  const float c = cosb[tpos * 64 + i], s = sinb[tpos * 64 + i];
  p[0] = f2b(x0 * c - x1 * s);
  p[1] = f2b(x0 * s + x1 * c);
}

// --------------------------------------------------------------- attention --
// one block (128 threads) per (b,h,t) query row over packed qkv [M][3072].
__global__ __launch_bounds__(128) void attn_k(const bf16* __restrict__ qkv,
                                              bf16* __restrict__ out) {
  const int bid = blockIdx.x;
  const int tq = bid & (Tc - 1);
  const int h = (bid >> 10) & (Hc - 1);
  const int b = bid >> 14;
  const int kv = h >> 2;
  const int tid = threadIdx.x;
  __shared__ float qs[DHc];
  __shared__ float sc[Tc];
  __shared__ float wmax[2], wsum[2];
  const bf16* qrow = qkv + (size_t)(b * Tc + tq) * Nqkv + h * DHc;
  qs[tid] = b2f(qrow[tid]) * 0.08838834764831845f;
  __syncthreads();
  const int len = tq + 1;
  const bf16* kbase = qkv + (size_t)(b * Tc) * Nqkv + Hc * DHc + kv * DHc;
  float lmax = -1e30f;
  for (int s = tid; s < len; s += 128) {
    const uint4* kp = reinterpret_cast<const uint4*>(kbase + (size_t)s * Nqkv);
    float dot = 0.f;
#pragma unroll
    for (int c = 0; c < DHc / 8; ++c) {
      union { uint4 v; bf16 h[8]; } uv;
      uv.v = kp[c];
#pragma unroll
      for (int j = 0; j < 8; ++j) dot += qs[c * 8 + j] * b2f(uv.h[j]);
    }
    sc[s] = dot;
    lmax = fmaxf(lmax, dot);
  }
#pragma unroll
  for (int off = 32; off > 0; off >>= 1) lmax = fmaxf(lmax, __shfl_down(lmax, off, 64));
  const int lane = tid & 63, wid = tid >> 6;
  if (lane == 0) wmax[wid] = lmax;
  __syncthreads();
  const float m = fmaxf(wmax[0], wmax[1]);
  float lsum = 0.f;
  for (int s = tid; s < len; s += 128) {
    float e = __expf(sc[s] - m);
    sc[s] = e;
    lsum += e;
  }
#pragma unroll
  for (int off = 32; off > 0; off >>= 1) lsum += __shfl_down(lsum, off, 64);
  if (lane == 0) wsum[wid] = lsum;
  __syncthreads();
  const float inv_denom = 1.f / (wsum[0] + wsum[1]);
  const bf16* vbase = kbase + HKVc * DHc + tid;
  float accd = 0.f;
  for (int s = 0; s < len; ++s) accd += sc[s] * b2f(vbase[(size_t)s * Nqkv]);
  out[(size_t)(b * Tc + tq) * Dc + h * DHc + tid] = f2b(accd * inv_denom);
}

// ------------------------------------------------------------------ launch --
extern "C" void kernel_launch(void* const* d_in, const int* in_sizes, int n_in,
                              void* d_out, int out_size, void* d_ws, size_t ws_size,
                              hipStream_t stream) {
  const float* x    = (const float*)d_in[0];
  const float* fcos = (const float*)d_in[1];
  const float* fsin = (const float*)d_in[2];
  const float* wn1  = (const float*)d_in[3];
  const float* wn2  = (const float*)d_in[4];
  const float* wq   = (const float*)d_in[5];
  const float* wk   = (const float*)d_in[6];
  const float* wv   = (const float*)d_in[7];
  const float* wo   = (const float*)d_in[8];
  const float* w1   = (const float*)d_in[9];
  const float* w2   = (const float*)d_in[10];
  const float* w3   = (const float*)d_in[11];

  char* p = (char*)d_ws;
  bf16* wqkv_t = (bf16*)p;                 p += (size_t)Nqkv * Dc * 2;   // 12.58 MB
  bf16* qkv    = (bf16*)p;                 p += (size_t)Mr * Nqkv * 2;   // 12.58 MB
  float* xat   = (float*)d_ws;             // aliases wqkv_t+qkv (dead by then), 16.8 MB
  bf16* wo_t = (bf16*)p;                   p += (size_t)Dc * Dc * 2;     // 8.39 MB
  bf16* w1t  = (bf16*)p;                   p += (size_t)Fc * Dc * 2;     // 23.07 MB
  bf16* w2t  = w1t;                        // aliases w1t (dead after ffn_dual)
  bf16* w3t  = (bf16*)p;                   p += (size_t)Fc * Dc * 2;     // 23.07 MB
  bf16* xn   = (bf16*)p;                   p += (size_t)Mr * Dc * 2;     // 8.39 MB (reused as h)
  bf16* ao   = (bf16*)p;                   p += (size_t)Mr * Dc * 2;     // 8.39 MB
  bf16* act  = (bf16*)p;                   p += (size_t)Mr * Fc * 2;     // 23.07 MB
  bf16* hb = xn;

  const dim3 blk(256);
  // weight transpose+casts (fp32 [K][N] -> bf16 [N][K])
  tcast_k<<<dim3(32, 32), blk, 0, stream>>>(wq, wqkv_t, 2048, 2048);
  tcast_k<<<dim3(8, 32), blk, 0, stream>>>(wk, wqkv_t + (size_t)2048 * 2048, 512, 2048);
  tcast_k<<<dim3(8, 32), blk, 0, stream>>>(wv, wqkv_t + (size_t)2560 * 2048, 512, 2048);
  tcast_k<<<dim3(32, 32), blk, 0, stream>>>(wo, wo_t, 2048, 2048);
  tcast_k<<<dim3(88, 32), blk, 0, stream>>>(w1, w1t, 5632, 2048);
  tcast_k<<<dim3(88, 32), blk, 0, stream>>>(w3, w3t, 5632, 2048);

  rmsnorm_k<<<Mr, blk, 0, stream>>>(x, wn1, xn);
  gemm128<false><<<dim3(Nqkv / 128, Mr / 128), blk, 0, stream>>>(xn, wqkv_t, nullptr, qkv, Nqkv, Dc);
  {
    int total = Mr * Hc * 64;
    rope_k<<<(total + 255) / 256, blk, 0, stream>>>(qkv, fcos, fsin, Hc, 0, total);
    total = Mr * HKVc * 64;
    rope_k<<<(total + 255) / 256, blk, 0, stream>>>(qkv, fcos, fsin, HKVc, Hc * DHc, total);
  }
  attn_k<<<Bc * Hc * Tc, dim3(128), 0, stream>>>(qkv, ao);
  gemm128<true><<<dim3(Dc / 128, Mr / 128), blk, 0, stream>>>(ao, wo_t, x, xat, Dc, Dc);
  rmsnorm_k<<<Mr, blk, 0, stream>>>(xat, wn2, hb);
  ffn_dual<<<dim3(Fc / 128, Mr / 64), blk, 0, stream>>>(hb, w1t, w3t, act, Dc);
  tcast_k<<<dim3(32, 88), blk, 0, stream>>>(w2, w2t, 2048, 5632);
  gemm128<true><<<dim3(Dc / 128, Mr / 128), blk, 0, stream>>>(act, w2t, xat, (float*)d_out, Dc, Fc);
}

// Round 5
// 665.131 us; speedup vs baseline: 9.2213x; 2.5241x over previous
//
#include <hip/hip_runtime.h>
#include <hip/hip_bf16.h>
#include <math.h>

typedef __hip_bfloat16 bf16;
typedef __attribute__((ext_vector_type(8))) short bf16x8;   // 8 bf16 = 4 VGPR
typedef __attribute__((ext_vector_type(4))) float f32x4;

__device__ __forceinline__ float b2f(bf16 v) { return __bfloat162float(v); }
__device__ __forceinline__ bf16  f2b(float v) { return __float2bfloat16(v); }

constexpr int Bc = 2, Tc = 1024, Dc = 2048, Hc = 16, HKVc = 4, DHc = 128, Fc = 5632;
constexpr int Mr = Bc * Tc;                      // 2048 rows
constexpr int Nqkv = Hc * DHc + 2 * HKVc * DHc;  // 3072

// async 16B global->LDS (lands at wave-uniform base + lane*16)
__device__ __forceinline__ void g2l16(void* lds, const void* g) {
  __builtin_amdgcn_global_load_lds(
      (const __attribute__((address_space(1))) unsigned int*)g,
      (__attribute__((address_space(3))) unsigned int*)lds, 16, 0, 0);
}

// ------------------------------------------------------- transpose + cast ---
// src fp32 [K][N] row-major  ->  dst bf16 [N][K] row-major (B^T for MFMA GEMM)
__global__ __launch_bounds__(256) void tcast_k(const float* __restrict__ src,
                                               bf16* __restrict__ dst,
                                               int N, int K) {
  __shared__ bf16 tile[64][68];
  const int t = threadIdx.x;
  const int n0 = blockIdx.x * 64, k0 = blockIdx.y * 64;
#pragma unroll
  for (int it = 0; it < 4; ++it) {
    const int kl = it * 16 + (t >> 4);
    const int nl = (t & 15) * 4;
    float4 v = *reinterpret_cast<const float4*>(src + (size_t)(k0 + kl) * N + n0 + nl);
    tile[kl][nl]     = f2b(v.x);
    tile[kl][nl + 1] = f2b(v.y);
    tile[kl][nl + 2] = f2b(v.z);
    tile[kl][nl + 3] = f2b(v.w);
  }
  __syncthreads();
  union { uint4 u; bf16 h[8]; } o;   // 16 B
#pragma unroll
  for (int it = 0; it < 2; ++it) {
    const int nl = it * 32 + (t >> 3);
    const int kl = (t & 7) * 8;
#pragma unroll
    for (int j = 0; j < 8; ++j) o.h[j] = tile[kl + j][nl];
    *reinterpret_cast<uint4*>(dst + (size_t)(n0 + nl) * K + k0 + kl) = o.u;
  }
}

// ---------------------------------------------------------------- RMSNorm ---
__global__ __launch_bounds__(256) void rmsnorm_k(const float* __restrict__ x,
                                                 const float* __restrict__ w,
                                                 bf16* __restrict__ out) {
  const size_t rbase = (size_t)blockIdx.x * Dc;
  float ss = 0.f;
  for (int i = threadIdx.x; i < Dc; i += 256) {
    float v = x[rbase + i];
    ss += v * v;
  }
#pragma unroll
  for (int off = 32; off > 0; off >>= 1) ss += __shfl_down(ss, off, 64);
  __shared__ float red[4];
  const int lane = threadIdx.x & 63, wid = threadIdx.x >> 6;
  if (lane == 0) red[wid] = ss;
  __syncthreads();
  const float scale = rsqrtf((red[0] + red[1] + red[2] + red[3]) / (float)Dc + 1e-6f);
  for (int i = threadIdx.x; i < Dc; i += 256)
    out[rbase + i] = f2b(x[rbase + i] * scale * w[i]);
}

// ----------------------------------------------------- MFMA GEMM (m97-ish) --
template <bool ADDRES>
__global__ __launch_bounds__(256) void gemm128(const bf16* __restrict__ A,
                                               const bf16* __restrict__ Bt,
                                               const float* __restrict__ Res,
                                               void* __restrict__ Out,
                                               int N, int K) {
  __shared__ __align__(16) bf16 As[128 * 32];
  __shared__ __align__(16) bf16 Bs[128 * 32];
  const int t = threadIdx.x;
  const int bm = blockIdx.y * 128, bn = blockIdx.x * 128;
  const int lane = t & 63, wv = t >> 6;
  const int wm = (wv & 1) * 64, wn = (wv >> 1) * 64;
  const int sr = t >> 2, sc = (t & 3) * 8;
  const bf16* ga = A + (size_t)(bm + sr) * K + sc;
  const bf16* gb = Bt + (size_t)(bn + sr) * K + sc;
  bf16* lA0 = As + sr * 32 + sc;
  bf16* lA1 = As + (64 + sr) * 32 + sc;
  bf16* lB0 = Bs + sr * 32 + sc;
  bf16* lB1 = Bs + (64 + sr) * 32 + sc;
  const size_t rstep = (size_t)64 * K;
  f32x4 acc[4][4] = {};
  const int fr = lane & 15, fko = (lane >> 4) * 8;
  for (int k0 = 0; k0 < K; k0 += 32) {
    __syncthreads();
    g2l16(lA0, ga + k0);
    g2l16(lA1, ga + rstep + k0);
    g2l16(lB0, gb + k0);
    g2l16(lB1, gb + rstep + k0);
    __syncthreads();
    bf16x8 af[4], bff[4];
#pragma unroll
    for (int i = 0; i < 4; ++i)
      af[i] = *reinterpret_cast<const bf16x8*>(As + (wm + i * 16 + fr) * 32 + fko);
#pragma unroll
    for (int j = 0; j < 4; ++j)
      bff[j] = *reinterpret_cast<const bf16x8*>(Bs + (wn + j * 16 + fr) * 32 + fko);
#pragma unroll
    for (int i = 0; i < 4; ++i)
#pragma unroll
      for (int j = 0; j < 4; ++j)
        acc[i][j] = __builtin_amdgcn_mfma_f32_16x16x32_bf16(af[i], bff[j], acc[i][j], 0, 0, 0);
  }
  const int er = (lane >> 4) * 4, ec = lane & 15;
#pragma unroll
  for (int i = 0; i < 4; ++i)
#pragma unroll
    for (int j = 0; j < 4; ++j) {
      const int row = bm + wm + i * 16 + er;
      const int col = bn + wn + j * 16 + ec;
#pragma unroll
      for (int r = 0; r < 4; ++r) {
        const size_t idx = (size_t)(row + r) * N + col;
        if (ADDRES) ((float*)Out)[idx] = Res[idx] + acc[i][j][r];
        else        ((bf16*)Out)[idx] = f2b(acc[i][j][r]);
      }
    }
}

// --------------------------------------------- fused FFN dual-B MFMA GEMM ---
__global__ __launch_bounds__(256) void ffn_dual(const bf16* __restrict__ A,
                                                const bf16* __restrict__ W1t,
                                                const bf16* __restrict__ W3t,
                                                bf16* __restrict__ act,
                                                int K) {
  __shared__ __align__(16) bf16 As[64 * 32];
  __shared__ __align__(16) bf16 B1s[128 * 32];
  __shared__ __align__(16) bf16 B3s[128 * 32];
  const int t = threadIdx.x;
  const int bm = blockIdx.y * 64, bn = blockIdx.x * 128;
  const int lane = t & 63, wv = t >> 6;
  const int wn = wv * 32;
  const int sr = t >> 2, sc = (t & 3) * 8;
  const bf16* ga = A + (size_t)(bm + sr) * K + sc;
  const bf16* g1 = W1t + (size_t)(bn + sr) * K + sc;
  const bf16* g3 = W3t + (size_t)(bn + sr) * K + sc;
  bf16* lA = As + sr * 32 + sc;
  bf16* l10 = B1s + sr * 32 + sc;
  bf16* l11 = B1s + (64 + sr) * 32 + sc;
  bf16* l30 = B3s + sr * 32 + sc;
  bf16* l31 = B3s + (64 + sr) * 32 + sc;
  const size_t rstep = (size_t)64 * K;
  f32x4 acc1[4][2] = {}, acc3[4][2] = {};
  const int fr = lane & 15, fko = (lane >> 4) * 8;
  for (int k0 = 0; k0 < K; k0 += 32) {
    __syncthreads();
    g2l16(lA, ga + k0);
    g2l16(l10, g1 + k0);
    g2l16(l11, g1 + rstep + k0);
    g2l16(l30, g3 + k0);
    g2l16(l31, g3 + rstep + k0);
    __syncthreads();
    bf16x8 af[4], b1[2], b3[2];
#pragma unroll
    for (int i = 0; i < 4; ++i)
      af[i] = *reinterpret_cast<const bf16x8*>(As + (i * 16 + fr) * 32 + fko);
#pragma unroll
    for (int j = 0; j < 2; ++j) {
      b1[j] = *reinterpret_cast<const bf16x8*>(B1s + (wn + j * 16 + fr) * 32 + fko);
      b3[j] = *reinterpret_cast<const bf16x8*>(B3s + (wn + j * 16 + fr) * 32 + fko);
    }
#pragma unroll
    for (int i = 0; i < 4; ++i)
#pragma unroll
      for (int j = 0; j < 2; ++j) {
        acc1[i][j] = __builtin_amdgcn_mfma_f32_16x16x32_bf16(af[i], b1[j], acc1[i][j], 0, 0, 0);
        acc3[i][j] = __builtin_amdgcn_mfma_f32_16x16x32_bf16(af[i], b3[j], acc3[i][j], 0, 0, 0);
      }
  }
  const int er = (lane >> 4) * 4, ec = lane & 15;
#pragma unroll
  for (int i = 0; i < 4; ++i)
#pragma unroll
    for (int j = 0; j < 2; ++j) {
      const int row = bm + i * 16 + er;
      const int col = bn + wn + j * 16 + ec;
#pragma unroll
      for (int r = 0; r < 4; ++r) {
        const float g = acc1[i][j][r], u = acc3[i][j][r];
        const float sg = g / (1.f + __expf(-g));
        act[(size_t)(row + r) * Fc + col] = f2b(sg * u);
      }
    }
}

// ---------------------------------------------- repack: RoPE + Q/K/V split --
// qkv packed [M][3072] -> Qr[B,H,T,DH], Kr[B,HKV,T,DH] (RoPE'd), Vt[B,HKV,DH,T]
__global__ __launch_bounds__(256) void repack_k(const bf16* __restrict__ qkv,
                                                const float* __restrict__ cosb,
                                                const float* __restrict__ sinb,
                                                bf16* __restrict__ Qr,
                                                bf16* __restrict__ Kr,
                                                bf16* __restrict__ Vt) {
  const int bt = blockIdx.x;
  const int b = bt >> 10, tp = bt & (Tc - 1);
  const int t0 = threadIdx.x;
  const bf16* row = qkv + (size_t)bt * Nqkv;
#pragma unroll
  for (int k = 0; k < 4; ++k) {      // Q: 1024 rope pairs
    int p2 = k * 256 + t0;
    int hh = p2 >> 6, i = p2 & 63;
    float c = cosb[tp * 64 + i], sn = sinb[tp * 64 + i];
    float x0 = b2f(row[hh * 128 + 2 * i]), x1 = b2f(row[hh * 128 + 2 * i + 1]);
    bf16* dst = Qr + ((size_t)(b * Hc + hh) * Tc + tp) * DHc + 2 * i;
    dst[0] = f2b(x0 * c - x1 * sn);
    dst[1] = f2b(x0 * sn + x1 * c);
  }
  {                                   // K: 256 rope pairs
    int hh = t0 >> 6, i = t0 & 63;
    float c = cosb[tp * 64 + i], sn = sinb[tp * 64 + i];
    float x0 = b2f(row[2048 + hh * 128 + 2 * i]), x1 = b2f(row[2048 + hh * 128 + 2 * i + 1]);
    bf16* dst = Kr + ((size_t)(b * HKVc + hh) * Tc + tp) * DHc + 2 * i;
    dst[0] = f2b(x0 * c - x1 * sn);
    dst[1] = f2b(x0 * sn + x1 * c);
  }
#pragma unroll
  for (int k = 0; k < 2; ++k) {      // V: 512 elems, transposed store
    int e = k * 256 + t0;
    int kvh = e >> 7, dd = e & 127;
    Vt[((size_t)(b * HKVc + kvh) * DHc + dd) * Tc + tp] = row[2560 + e];
  }
}

// ----------------------------------------------------- MFMA flash attention --
// block = (b, h, 64-row q-tile); 4 waves x 16 q-rows; 64-key tiles.
__global__ __launch_bounds__(256) void fattn(const bf16* __restrict__ Qr,
                                             const bf16* __restrict__ Kr,
                                             const bf16* __restrict__ Vt,
                                             bf16* __restrict__ ao) {
  __shared__ __align__(16) bf16 Ks[64 * 136];    // [key][d], +8 pad
  __shared__ __align__(16) bf16 Vts[128 * 72];   // [d][key], +8 pad
  __shared__ __align__(16) bf16 Ps[4][16 * 72];  // per-wave P
  const int idx = blockIdx.x;
  const int r = idx & 15;
  const int qt = (r & 1) ? (15 - (r >> 1)) : (r >> 1);  // pair-balanced
  const int h = (idx >> 4) & 15;
  const int b = idx >> 8;
  const int kv = h >> 2;
  const int t = threadIdx.x, lane = t & 63, wv = t >> 6;
  const int fr = lane & 15, quad = lane >> 4;

  const bf16* Qbase = Qr + ((size_t)(b * Hc + h) * Tc + qt * 64) * DHc;
  const bf16* Kbase = Kr + (size_t)(b * HKVc + kv) * Tc * DHc;
  const bf16* Vbase = Vt + (size_t)(b * HKVc + kv) * DHc * Tc;

  bf16x8 qf[4];
#pragma unroll
  for (int c = 0; c < 4; ++c)
    qf[c] = *reinterpret_cast<const bf16x8*>(Qbase + (size_t)(wv * 16 + fr) * DHc + c * 32 + quad * 8);

  float m[4], l[4];
  f32x4 o[8] = {};
#pragma unroll
  for (int r2 = 0; r2 < 4; ++r2) { m[r2] = -3.0e38f; l[r2] = 0.f; }

  for (int kt = 0; kt <= qt; ++kt) {
    __syncthreads();
    {  // stage K tile [64][128] -> Ks[64][136]
      const bf16* src = Kbase + (size_t)kt * 64 * DHc;
#pragma unroll
      for (int i2 = 0; i2 < 4; ++i2) {
        int flat = i2 * 256 + t;           // 16B units
        int row = flat >> 4, c16 = flat & 15;
        uint4 v = *reinterpret_cast<const uint4*>(src + (size_t)row * DHc + c16 * 8);
        *reinterpret_cast<uint4*>(&Ks[row * 136 + c16 * 8]) = v;
      }
      // stage V tile [128 d][64 key] -> Vts[128][72]
#pragma unroll
      for (int i2 = 0; i2 < 4; ++i2) {
        int flat = i2 * 256 + t;
        int row = flat >> 3, c8 = flat & 7;
        uint4 v = *reinterpret_cast<const uint4*>(Vbase + (size_t)row * Tc + kt * 64 + c8 * 8);
        *reinterpret_cast<uint4*>(&Vts[row * 72 + c8 * 8]) = v;
      }
    }
    __syncthreads();
    // S = Q K^T  (16 MFMA)
    f32x4 s[4];
#pragma unroll
    for (int cb = 0; cb < 4; ++cb) {
      f32x4 acc = {};
#pragma unroll
      for (int kc = 0; kc < 4; ++kc) {
        bf16x8 kf = *reinterpret_cast<const bf16x8*>(&Ks[(cb * 16 + fr) * 136 + kc * 32 + quad * 8]);
        acc = __builtin_amdgcn_mfma_f32_16x16x32_bf16(qf[kc], kf, acc, 0, 0, 0);
      }
      s[cb] = acc * 0.08838834764831845f;
    }
    if (kt == qt) {  // causal mask, diagonal tile only
#pragma unroll
      for (int cb = 0; cb < 4; ++cb)
#pragma unroll
        for (int r2 = 0; r2 < 4; ++r2) {
          int key = cb * 16 + fr;
          int qg = wv * 16 + quad * 4 + r2;
          if (key > qg) s[cb][r2] = -3.0e38f;
        }
    }
    // online softmax
    float tm[4], ts[4];
#pragma unroll
    for (int r2 = 0; r2 < 4; ++r2)
      tm[r2] = fmaxf(fmaxf(s[0][r2], s[1][r2]), fmaxf(s[2][r2], s[3][r2]));
#pragma unroll
    for (int off = 1; off < 16; off <<= 1)
#pragma unroll
      for (int r2 = 0; r2 < 4; ++r2)
        tm[r2] = fmaxf(tm[r2], __shfl_xor(tm[r2], off, 64));
    float al[4];
#pragma unroll
    for (int r2 = 0; r2 < 4; ++r2) {
      float mn = fmaxf(m[r2], tm[r2]);
      al[r2] = __expf(m[r2] - mn);
      m[r2] = mn;
      ts[r2] = 0.f;
    }
#pragma unroll
    for (int cb = 0; cb < 4; ++cb)
#pragma unroll
      for (int r2 = 0; r2 < 4; ++r2) {
        float e = __expf(s[cb][r2] - m[r2]);
        s[cb][r2] = e;
        ts[r2] += e;
      }
#pragma unroll
    for (int off = 1; off < 16; off <<= 1)
#pragma unroll
      for (int r2 = 0; r2 < 4; ++r2)
        ts[r2] += __shfl_xor(ts[r2], off, 64);
#pragma unroll
    for (int r2 = 0; r2 < 4; ++r2) l[r2] = l[r2] * al[r2] + ts[r2];
#pragma unroll
    for (int db = 0; db < 8; ++db)
#pragma unroll
      for (int r2 = 0; r2 < 4; ++r2) o[db][r2] *= al[r2];
    // P: C-layout regs -> LDS -> A-layout frags
    bf16* pw = Ps[wv];
#pragma unroll
    for (int cb = 0; cb < 4; ++cb)
#pragma unroll
      for (int r2 = 0; r2 < 4; ++r2)
        pw[(quad * 4 + r2) * 72 + cb * 16 + fr] = f2b(s[cb][r2]);
    bf16x8 pa[2];
    pa[0] = *reinterpret_cast<const bf16x8*>(&pw[fr * 72 + quad * 8]);
    pa[1] = *reinterpret_cast<const bf16x8*>(&pw[fr * 72 + 32 + quad * 8]);
    // O += P V  (16 MFMA)
#pragma unroll
    for (int db = 0; db < 8; ++db) {
      bf16x8 v0 = *reinterpret_cast<const bf16x8*>(&Vts[(db * 16 + fr) * 72 + quad * 8]);
      bf16x8 v1 = *reinterpret_cast<const bf16x8*>(&Vts[(db * 16 + fr) * 72 + 32 + quad * 8]);
      o[db] = __builtin_amdgcn_mfma_f32_16x16x32_bf16(pa[0], v0, o[db], 0, 0, 0);
      o[db] = __builtin_amdgcn_mfma_f32_16x16x32_bf16(pa[1], v1, o[db], 0, 0, 0);
    }
  }
#pragma unroll
  for (int r2 = 0; r2 < 4; ++r2) {
    float inv = 1.f / l[r2];
    int qg = qt * 64 + wv * 16 + quad * 4 + r2;
    bf16* orow = ao + (size_t)(b * Tc + qg) * Dc + h * DHc;
#pragma unroll
    for (int db = 0; db < 8; ++db)
      orow[db * 16 + fr] = f2b(o[db][r2] * inv);
  }
}

// ------------------------------------------------------------------ launch --
extern "C" void kernel_launch(void* const* d_in, const int* in_sizes, int n_in,
                              void* d_out, int out_size, void* d_ws, size_t ws_size,
                              hipStream_t stream) {
  const float* x    = (const float*)d_in[0];
  const float* fcos = (const float*)d_in[1];
  const float* fsin = (const float*)d_in[2];
  const float* wn1  = (const float*)d_in[3];
  const float* wn2  = (const float*)d_in[4];
  const float* wq   = (const float*)d_in[5];
  const float* wk   = (const float*)d_in[6];
  const float* wv   = (const float*)d_in[7];
  const float* wo   = (const float*)d_in[8];
  const float* w1   = (const float*)d_in[9];
  const float* w2   = (const float*)d_in[10];
  const float* w3   = (const float*)d_in[11];

  char* p = (char*)d_ws;
  bf16* wqkv_t = (bf16*)p;                 p += (size_t)Nqkv * Dc * 2;   // 12.58 MB
  bf16* qkv    = (bf16*)p;                 p += (size_t)Mr * Nqkv * 2;   // 12.58 MB
  float* xat   = (float*)d_ws;             // aliases wqkv_t+qkv (dead by wo-gemm)
  bf16* wo_t = (bf16*)p;                   p += (size_t)Dc * Dc * 2;     // 8.39 MB
  bf16* w1t  = (bf16*)p;                   p += (size_t)Fc * Dc * 2;     // 23.07 MB
  bf16* w2t  = w1t;                        // aliases w1t (dead after ffn_dual)
  bf16* w3t  = (bf16*)p;                   p += (size_t)Fc * Dc * 2;     // 23.07 MB
  bf16* xn   = (bf16*)p;                   p += (size_t)Mr * Dc * 2;     // 8.39 MB (reused as h)
  bf16* ao   = (bf16*)p;                   p += (size_t)Mr * Dc * 2;     // 8.39 MB
  bf16* act  = (bf16*)p;                   p += (size_t)Mr * Fc * 2;     // 23.07 MB
  bf16* hb = xn;
  // Qr/Kr/Vt alias the act region (act written only after attention is done)
  bf16* Qr = act;                                        // 8.39 MB
  bf16* Kr = act + (size_t)Mr * Hc * DHc;                // 2.10 MB
  bf16* Vtb = Kr + (size_t)Mr * HKVc * DHc;              // 2.10 MB

  const dim3 blk(256);
  tcast_k<<<dim3(32, 32), blk, 0, stream>>>(wq, wqkv_t, 2048, 2048);
  tcast_k<<<dim3(8, 32), blk, 0, stream>>>(wk, wqkv_t + (size_t)2048 * 2048, 512, 2048);
  tcast_k<<<dim3(8, 32), blk, 0, stream>>>(wv, wqkv_t + (size_t)2560 * 2048, 512, 2048);
  tcast_k<<<dim3(32, 32), blk, 0, stream>>>(wo, wo_t, 2048, 2048);
  tcast_k<<<dim3(88, 32), blk, 0, stream>>>(w1, w1t, 5632, 2048);
  tcast_k<<<dim3(88, 32), blk, 0, stream>>>(w3, w3t, 5632, 2048);

  rmsnorm_k<<<Mr, blk, 0, stream>>>(x, wn1, xn);
  gemm128<false><<<dim3(Nqkv / 128, Mr / 128), blk, 0, stream>>>(xn, wqkv_t, nullptr, qkv, Nqkv, Dc);
  repack_k<<<Mr, blk, 0, stream>>>(qkv, fcos, fsin, Qr, Kr, Vtb);
  fattn<<<Bc * Hc * 16, blk, 0, stream>>>(Qr, Kr, Vtb, ao);
  gemm128<true><<<dim3(Dc / 128, Mr / 128), blk, 0, stream>>>(ao, wo_t, x, xat, Dc, Dc);
  rmsnorm_k<<<Mr, blk, 0, stream>>>(xat, wn2, hb);
  ffn_dual<<<dim3(Fc / 128, Mr / 64), blk, 0, stream>>>(hb, w1t, w3t, act, Dc);
  tcast_k<<<dim3(32, 88), blk, 0, stream>>>(w2, w2t, 2048, 5632);
  gemm128<true><<<dim3(Dc / 128, Mr / 128), blk, 0, stream>>>(act, w2t, xat, (float*)d_out, Dc, Fc);
}